// Round 1
// baseline (1080.272 us; speedup 1.0000x reference)
//
#include <hip/hip_runtime.h>

// MultiHeadAttention_Discrete — fp32 baseline, structured for later optimization.
// ws layout (floats): Q[16*2048*64] | V[16*2048*64] | lse[16*2048] | att[16*2048*64] | gs[2*2048*512]
// total ws = 33,685,504 bytes.

#define NHEAD 8
#define NBATCH 2
#define SEQL 2048
#define BHN 16
#define TEMPF 0.006737946999085467f

__device__ __forceinline__ float gumbelf(float u) {
  return -__logf(-__logf(u + 1e-10f) + 1e-10f);
}
__device__ __forceinline__ float bmax16(float v) {
  v = fmaxf(v, __shfl_xor(v, 1));
  v = fmaxf(v, __shfl_xor(v, 2));
  v = fmaxf(v, __shfl_xor(v, 4));
  v = fmaxf(v, __shfl_xor(v, 8));
  return v;
}
__device__ __forceinline__ float bsum16(float v) {
  v += __shfl_xor(v, 1);
  v += __shfl_xor(v, 2);
  v += __shfl_xor(v, 4);
  v += __shfl_xor(v, 8);
  return v;
}

// Y[m][c] = sum_k X[m][k]*W[c][k] + bias[c];  M=4096, N=512, K=512.
// headsplit=1: scatter Y to [(head*NBATCH+b)][s][d] layout (head = n-tile).
__global__ __launch_bounds__(256) void gemm512(const float* __restrict__ X,
    const float* __restrict__ W, const float* __restrict__ bias,
    float* __restrict__ Y, int headsplit)
{
  __shared__ float Xt[64][68];   // pad 68: 2-way-max bank aliasing on b128 reads
  __shared__ float WT[64][68];   // W tile stored transposed [k][c]
  const int tid = threadIdx.x;
  const int tx = tid & 15, ty = tid >> 4;
  const int mt = blockIdx.x >> 3, nt = blockIdx.x & 7;
  const int m0 = mt << 6, n0 = nt << 6;
  float acc[4][4] = {};
  for (int kc = 0; kc < 8; ++kc) {
    if (kc) __syncthreads();
#pragma unroll
    for (int i = 0; i < 4; ++i) {
      const int f = (tid << 2) + i;
      const int r = f >> 4, k4 = (f & 15) << 2;
      *(float4*)&Xt[r][k4] = *(const float4*)&X[(size_t)(m0 + r) * 512 + (kc << 6) + k4];
      float4 w = *(const float4*)&W[(size_t)(n0 + r) * 512 + (kc << 6) + k4];
      WT[k4 + 0][r] = w.x; WT[k4 + 1][r] = w.y; WT[k4 + 2][r] = w.z; WT[k4 + 3][r] = w.w;
    }
    __syncthreads();
#pragma unroll 4
    for (int k4 = 0; k4 < 64; k4 += 4) {
      float4 A0 = *(const float4*)&Xt[(ty << 2) + 0][k4];
      float4 A1 = *(const float4*)&Xt[(ty << 2) + 1][k4];
      float4 A2 = *(const float4*)&Xt[(ty << 2) + 2][k4];
      float4 A3 = *(const float4*)&Xt[(ty << 2) + 3][k4];
      float4 B0 = *(const float4*)&WT[k4 + 0][tx << 2];
      float4 B1 = *(const float4*)&WT[k4 + 1][tx << 2];
      float4 B2 = *(const float4*)&WT[k4 + 2][tx << 2];
      float4 B3 = *(const float4*)&WT[k4 + 3][tx << 2];
      const float a[4][4] = {{A0.x,A0.y,A0.z,A0.w},{A1.x,A1.y,A1.z,A1.w},
                             {A2.x,A2.y,A2.z,A2.w},{A3.x,A3.y,A3.z,A3.w}};
      const float b[4][4] = {{B0.x,B0.y,B0.z,B0.w},{B1.x,B1.y,B1.z,B1.w},
                             {B2.x,B2.y,B2.z,B2.w},{B3.x,B3.y,B3.z,B3.w}};
#pragma unroll
      for (int i = 0; i < 4; ++i)
#pragma unroll
        for (int j = 0; j < 4; ++j)
          acc[i][j] += a[i][0]*b[0][j] + a[i][1]*b[1][j] + a[i][2]*b[2][j] + a[i][3]*b[3][j];
    }
  }
  const int c0 = n0 + (tx << 2);
  const float4 bv = *(const float4*)&bias[c0];
#pragma unroll
  for (int i = 0; i < 4; ++i) {
    const int m = m0 + (ty << 2) + i;
    float4 o = make_float4(acc[i][0] + bv.x, acc[i][1] + bv.y,
                           acc[i][2] + bv.z, acc[i][3] + bv.w);
    if (headsplit) {
      const int bb = m >> 11, s = m & 2047;
      *(float4*)&Y[(((size_t)(nt * NBATCH + bb) * SEQL + s) << 6) + (tx << 2)] = o;
    } else {
      *(float4*)&Y[((size_t)m << 9) + c0] = o;
    }
  }
}

// Fused attention: per 64-row block of one (head,batch):
//  pass1: S = Qi @ Qj^T (fp32), diag=-1e9; write raw s to logp region; online
//         (m1,l1) for log-softmax; t = s + gumbel(u); online M2 = max t; push
//         candidate j's with t > M2-0.62 (superset of all nonzero sample weights,
//         since exp(x/T) == 0 in fp32 for x < -0.588).
//  pass2: per row, gather candidates: recompute s (dot), p = exp((s+g-M2)/T),
//         att_out = sum(p*v)/sum(p).  Write lse for the logp fix kernel.
__global__ __launch_bounds__(256) void attn_fused(const float* __restrict__ Q,
    const float* __restrict__ V, const float* __restrict__ U,
    float* __restrict__ sraw, float* __restrict__ lse, float* __restrict__ att)
{
  __shared__ float Qi[64][68];
  __shared__ float QjT[64][68];
  __shared__ unsigned short cand[64][128];
  __shared__ int ccnt[64];
  const int tid = threadIdx.x;
  const int tx = tid & 15, ty = tid >> 4;
  // XCD-locality swizzle: same bh lands on same (assumed %8) XCD for Q/V L2 reuse
  const int bh = ((blockIdx.x & 7) << 1) | ((blockIdx.x >> 3) & 1);
  const int rb = blockIdx.x >> 4;
  const int r0 = rb << 6;
  const float* Qh = Q + (((size_t)bh * SEQL) << 6);
  const float* Vh = V + (((size_t)bh * SEQL) << 6);
  if (tid < 64) ccnt[tid] = 0;
#pragma unroll
  for (int i = 0; i < 4; ++i) {
    const int f = (tid << 2) + i;
    const int r = f >> 4, k4 = (f & 15) << 2;
    *(float4*)&Qi[r][k4] = *(const float4*)&Qh[((size_t)(r0 + r) << 6) + k4];
  }
  float m1[4], l1[4], M2[4];
#pragma unroll
  for (int i = 0; i < 4; ++i) { m1[i] = -1e30f; l1[i] = 0.f; M2[i] = -1e30f; }
  __syncthreads();

  for (int jt = 0; jt < 32; ++jt) {
    if (jt) __syncthreads();
#pragma unroll
    for (int i = 0; i < 4; ++i) {
      const int f = (tid << 2) + i;
      const int c = f >> 4, k4 = (f & 15) << 2;
      float4 w = *(const float4*)&Qh[((size_t)((jt << 6) + c) << 6) + k4];
      QjT[k4 + 0][c] = w.x; QjT[k4 + 1][c] = w.y; QjT[k4 + 2][c] = w.z; QjT[k4 + 3][c] = w.w;
    }
    __syncthreads();
    float s4[4][4] = {};
#pragma unroll 4
    for (int k4 = 0; k4 < 64; k4 += 4) {
      float4 A0 = *(const float4*)&Qi[(ty << 2) + 0][k4];
      float4 A1 = *(const float4*)&Qi[(ty << 2) + 1][k4];
      float4 A2 = *(const float4*)&Qi[(ty << 2) + 2][k4];
      float4 A3 = *(const float4*)&Qi[(ty << 2) + 3][k4];
      float4 B0 = *(const float4*)&QjT[k4 + 0][tx << 2];
      float4 B1 = *(const float4*)&QjT[k4 + 1][tx << 2];
      float4 B2 = *(const float4*)&QjT[k4 + 2][tx << 2];
      float4 B3 = *(const float4*)&QjT[k4 + 3][tx << 2];
      const float a[4][4] = {{A0.x,A0.y,A0.z,A0.w},{A1.x,A1.y,A1.z,A1.w},
                             {A2.x,A2.y,A2.z,A2.w},{A3.x,A3.y,A3.z,A3.w}};
      const float b[4][4] = {{B0.x,B0.y,B0.z,B0.w},{B1.x,B1.y,B1.z,B1.w},
                             {B2.x,B2.y,B2.z,B2.w},{B3.x,B3.y,B3.z,B3.w}};
#pragma unroll
      for (int i = 0; i < 4; ++i)
#pragma unroll
        for (int j = 0; j < 4; ++j)
          s4[i][j] += a[i][0]*b[0][j] + a[i][1]*b[1][j] + a[i][2]*b[2][j] + a[i][3]*b[3][j];
    }
#pragma unroll
    for (int i = 0; i < 4; ++i) {
      const int lr = (ty << 2) + i;
      const int gr = r0 + lr;
      const int gc0 = (jt << 6) + (tx << 2);
#pragma unroll
      for (int jj = 0; jj < 4; ++jj)
        if (gr == gc0 + jj) s4[i][jj] = -1e9f;
      const size_t rowb = ((size_t)bh * SEQL + gr) * SEQL;
      *(float4*)&sraw[rowb + gc0] = make_float4(s4[i][0], s4[i][1], s4[i][2], s4[i][3]);
      const float4 uu = *(const float4*)&U[rowb + gc0];
      const float t0 = s4[i][0] + gumbelf(uu.x);
      const float t1 = s4[i][1] + gumbelf(uu.y);
      const float t2 = s4[i][2] + gumbelf(uu.z);
      const float t3 = s4[i][3] + gumbelf(uu.w);
      float sm = bmax16(fmaxf(fmaxf(s4[i][0], s4[i][1]), fmaxf(s4[i][2], s4[i][3])));
      const float nm = fmaxf(m1[i], sm);
      float es = __expf(s4[i][0] - nm) + __expf(s4[i][1] - nm)
               + __expf(s4[i][2] - nm) + __expf(s4[i][3] - nm);
      es = bsum16(es);
      l1[i] = l1[i] * __expf(m1[i] - nm) + es;
      m1[i] = nm;
      float tm = bmax16(fmaxf(fmaxf(t0, t1), fmaxf(t2, t3)));
      const float nM = fmaxf(M2[i], tm);
      M2[i] = nM;
      const float thr = nM - 0.62f;
      if (t0 > thr) { int z = atomicAdd(&ccnt[lr], 1); if (z < 128) cand[lr][z] = (unsigned short)(gc0 + 0); }
      if (t1 > thr) { int z = atomicAdd(&ccnt[lr], 1); if (z < 128) cand[lr][z] = (unsigned short)(gc0 + 1); }
      if (t2 > thr) { int z = atomicAdd(&ccnt[lr], 1); if (z < 128) cand[lr][z] = (unsigned short)(gc0 + 2); }
      if (t3 > thr) { int z = atomicAdd(&ccnt[lr], 1); if (z < 128) cand[lr][z] = (unsigned short)(gc0 + 3); }
    }
  }
  __syncthreads();
#pragma unroll 1
  for (int i = 0; i < 4; ++i) {
    const int lr = (ty << 2) + i;
    const int gr = r0 + lr;
    int n = ccnt[lr]; n = (n < 128) ? n : 128;
    const size_t rowb = ((size_t)bh * SEQL + gr) * SEQL;
    const float4 qi = *(const float4*)&Qi[lr][tx << 2];
    float l2 = 0.f, ax = 0.f, ay = 0.f, az = 0.f, aw = 0.f;
    for (int c = 0; c < n; ++c) {
      const int j = cand[lr][c];
      const float4 qj = *(const float4*)&Qh[((size_t)j << 6) + (tx << 2)];
      float s = qi.x*qj.x + qi.y*qj.y + qi.z*qj.z + qi.w*qj.w;
      s = bsum16(s);
      if (j == gr) s = -1e9f;
      const float g = gumbelf(U[rowb + j]);
      const float p = __expf((s + g - M2[i]) / TEMPF);
      l2 += p;
      const float4 vv = *(const float4*)&Vh[((size_t)j << 6) + (tx << 2)];
      ax += p * vv.x; ay += p * vv.y; az += p * vv.z; aw += p * vv.w;
    }
    const float inv = 1.0f / l2;
    *(float4*)&att[(((size_t)bh * SEQL + gr) << 6) + (tx << 2)] =
        make_float4(ax * inv, ay * inv, az * inv, aw * inv);
    if (tx == 0) lse[bh * SEQL + gr] = m1[i] + __logf(l1[i]);
  }
}

// logp[bh][i][j] = raw_s - lse[bh][i]; diagonal = -1e9 - lse. In place, float4.
__global__ __launch_bounds__(256) void logp_fix(float* __restrict__ p,
                                                const float* __restrict__ lse)
{
  const size_t nf4 = (size_t)BHN * SEQL * (SEQL / 4);
  const size_t stride = (size_t)gridDim.x * 256;
  for (size_t f = (size_t)blockIdx.x * 256 + threadIdx.x; f < nf4; f += stride) {
    const int j4 = (int)(f & 511) << 2;
    const size_t row = f >> 9;
    const int i = (int)(row & 2047);
    const int bh = (int)(row >> 11);
    const float ls = lse[(bh << 11) + i];
    float4 v = ((float4*)p)[f];
    v.x -= ls; v.y -= ls; v.z -= ls; v.w -= ls;
    const int d = i - j4;
    if (d >= 0 && d < 4) ((float*)&v)[d] = -1e9f - ls;
    ((float4*)p)[f] = v;
  }
}

// Per-head FF tube (64->128 relu ->64) + pairwise Gumbel-softmax (GS_DIM=2).
// One thread per token; w1/w2T staged in LDS (64 KB).
__global__ __launch_bounds__(128) void tubes(const float* __restrict__ att,
    const float* __restrict__ ff_w1, const float* __restrict__ ff_b1,
    const float* __restrict__ ff_w2, const float* __restrict__ ff_b2,
    const float* __restrict__ u_gs, float* __restrict__ gs)
{
  __shared__ float w1s[128 * 64];
  __shared__ float w2Ts[128 * 64];   // [j][o]
  const int tid = threadIdx.x;
  const int n = blockIdx.x >> 5;
  const int chunk = blockIdx.x & 31;
  const float* w1 = ff_w1 + n * 8192;
  const float* w2 = ff_w2 + n * 8192;
#pragma unroll
  for (int i = 0; i < 16; ++i) {
    const int f = i * 128 + tid;
    ((float4*)w1s)[f] = ((const float4*)w1)[f];
    const int o = f >> 5, j4 = (f & 31) << 2;
    float4 v = ((const float4*)w2)[f];
    w2Ts[(j4 + 0) * 64 + o] = v.x; w2Ts[(j4 + 1) * 64 + o] = v.y;
    w2Ts[(j4 + 2) * 64 + o] = v.z; w2Ts[(j4 + 3) * 64 + o] = v.w;
  }
  __syncthreads();
  const int token = chunk * 128 + tid;
  const int b = token >> 11, s = token & 2047;
  const float* ap = att + (((size_t)(n * NBATCH + b) * SEQL + s) << 6);
  float a[64];
#pragma unroll
  for (int k4 = 0; k4 < 64; k4 += 4) {
    float4 v = *(const float4*)&ap[k4];
    a[k4] = v.x; a[k4 + 1] = v.y; a[k4 + 2] = v.z; a[k4 + 3] = v.w;
  }
  float dm[64] = {};
  for (int j = 0; j < 128; ++j) {
    float h = ff_b1[n * 128 + j];
#pragma unroll
    for (int k4 = 0; k4 < 64; k4 += 4) {
      float4 w = *(const float4*)&w1s[(j << 6) + k4];
      h += w.x * a[k4] + w.y * a[k4 + 1] + w.z * a[k4 + 2] + w.w * a[k4 + 3];
    }
    h = fmaxf(h, 0.f);
#pragma unroll
    for (int o4 = 0; o4 < 64; o4 += 4) {
      float4 w = *(const float4*)&w2Ts[(j << 6) + o4];
      dm[o4] += w.x * h; dm[o4 + 1] += w.y * h; dm[o4 + 2] += w.z * h; dm[o4 + 3] += w.w * h;
    }
  }
  const float* up = u_gs + (((size_t)(n * NBATCH + b) * SEQL + s) << 6);
  float* gp = gs + (((size_t)(b * SEQL + s)) << 9) + (n << 6);
  const float* b2 = ff_b2 + (n << 6);
#pragma unroll
  for (int q = 0; q < 16; ++q) {
    const float4 uu = *(const float4*)&up[q << 2];
    const float d0 = dm[(q << 2) + 0] + b2[(q << 2) + 0];
    const float d1 = dm[(q << 2) + 1] + b2[(q << 2) + 1];
    const float d2 = dm[(q << 2) + 2] + b2[(q << 2) + 2];
    const float d3 = dm[(q << 2) + 3] + b2[(q << 2) + 3];
    const float z0 = d0 + gumbelf(uu.x), z1 = d1 + gumbelf(uu.y);
    const float z2 = d2 + gumbelf(uu.z), z3 = d3 + gumbelf(uu.w);
    const float ma = fmaxf(z0, z1), mb = fmaxf(z2, z3);
    const float e0 = __expf((z0 - ma) / TEMPF), e1 = __expf((z1 - ma) / TEMPF);
    const float e2 = __expf((z2 - mb) / TEMPF), e3 = __expf((z3 - mb) / TEMPF);
    const float ia = 1.0f / (e0 + e1), ib = 1.0f / (e2 + e3);
    *(float4*)&gp[q << 2] = make_float4(e0 * ia, e1 * ia, e2 * ib, e3 * ib);
  }
}

extern "C" void kernel_launch(void* const* d_in, const int* in_sizes, int n_in,
                              void* d_out, int out_size, void* d_ws, size_t ws_size,
                              hipStream_t stream) {
  const float* kq    = (const float*)d_in[0];
  const float* v     = (const float*)d_in[1];
  const float* w_kq  = (const float*)d_in[2];
  const float* b_kq  = (const float*)d_in[3];
  const float* w_v   = (const float*)d_in[4];
  const float* b_v   = (const float*)d_in[5];
  const float* ff_w1 = (const float*)d_in[6];
  const float* ff_b1 = (const float*)d_in[7];
  const float* ff_w2 = (const float*)d_in[8];
  const float* ff_b2 = (const float*)d_in[9];
  const float* fc_w  = (const float*)d_in[10];
  const float* fc_b  = (const float*)d_in[11];
  const float* u_at  = (const float*)d_in[12];
  const float* u_gs  = (const float*)d_in[13];
  float* out  = (float*)d_out;
  float* logp = out + (size_t)NBATCH * SEQL * 512;   // 2,097,152
  float* ws   = (float*)d_ws;
  float* Q    = ws;
  float* V    = Q + (size_t)BHN * SEQL * 64;
  float* lse  = V + (size_t)BHN * SEQL * 64;
  float* att  = lse + (size_t)BHN * SEQL;
  float* gs   = att + (size_t)BHN * SEQL * 64;

  gemm512<<<512, 256, 0, stream>>>(kq, w_kq, b_kq, Q, 1);
  gemm512<<<512, 256, 0, stream>>>(v, w_v, b_v, V, 1);
  attn_fused<<<512, 256, 0, stream>>>(Q, V, u_at, logp, lse, att);
  logp_fix<<<8192, 256, 0, stream>>>(logp, lse);
  tubes<<<256, 128, 0, stream>>>(att, ff_w1, ff_b1, ff_w2, ff_b2, u_gs, gs);
  gemm512<<<512, 256, 0, stream>>>(gs, fc_w, fc_b, out, 0);
}

// Round 2
// 1062.389 us; speedup vs baseline: 1.0168x; 1.0168x over previous
//
#include <hip/hip_runtime.h>

// MultiHeadAttention_Discrete — fp32, round 2.
// attn v2: pass1 = QK + lane-local online (m,l) + global-running M2 + candidates
//          (no global writes); merge; pass2 = recompute QK, write logp = s - lse
//          directly (logp_fix kernel eliminated), candidate-gather PV.
// ws layout (floats): Q[16*2048*64] | V[16*2048*64] | att[16*2048*64] | gs[2*2048*512]

#define NHEAD 8
#define NBATCH 2
#define SEQL 2048
#define BHN 16
#define TEMPF 0.006737946999085467f

__device__ __forceinline__ float gumbelf(float u) {
  return -__logf(-__logf(u + 1e-10f) + 1e-10f);
}
__device__ __forceinline__ float bmax16(float v) {
  v = fmaxf(v, __shfl_xor(v, 1));
  v = fmaxf(v, __shfl_xor(v, 2));
  v = fmaxf(v, __shfl_xor(v, 4));
  v = fmaxf(v, __shfl_xor(v, 8));
  return v;
}
__device__ __forceinline__ float bsum16(float v) {
  v += __shfl_xor(v, 1);
  v += __shfl_xor(v, 2);
  v += __shfl_xor(v, 4);
  v += __shfl_xor(v, 8);
  return v;
}

// Y[m][c] = sum_k X[m][k]*W[c][k] + bias[c];  M=4096, N=512, K=512.
__global__ __launch_bounds__(256) void gemm512(const float* __restrict__ X,
    const float* __restrict__ W, const float* __restrict__ bias,
    float* __restrict__ Y, int headsplit)
{
  __shared__ float Xt[64][68];
  __shared__ float WT[64][68];
  const int tid = threadIdx.x;
  const int tx = tid & 15, ty = tid >> 4;
  const int mt = blockIdx.x >> 3, nt = blockIdx.x & 7;
  const int m0 = mt << 6, n0 = nt << 6;
  float acc[4][4] = {};
  for (int kc = 0; kc < 8; ++kc) {
    if (kc) __syncthreads();
#pragma unroll
    for (int i = 0; i < 4; ++i) {
      const int f = (tid << 2) + i;
      const int r = f >> 4, k4 = (f & 15) << 2;
      *(float4*)&Xt[r][k4] = *(const float4*)&X[(size_t)(m0 + r) * 512 + (kc << 6) + k4];
      float4 w = *(const float4*)&W[(size_t)(n0 + r) * 512 + (kc << 6) + k4];
      WT[k4 + 0][r] = w.x; WT[k4 + 1][r] = w.y; WT[k4 + 2][r] = w.z; WT[k4 + 3][r] = w.w;
    }
    __syncthreads();
#pragma unroll 4
    for (int k4 = 0; k4 < 64; k4 += 4) {
      float4 A0 = *(const float4*)&Xt[(ty << 2) + 0][k4];
      float4 A1 = *(const float4*)&Xt[(ty << 2) + 1][k4];
      float4 A2 = *(const float4*)&Xt[(ty << 2) + 2][k4];
      float4 A3 = *(const float4*)&Xt[(ty << 2) + 3][k4];
      float4 B0 = *(const float4*)&WT[k4 + 0][tx << 2];
      float4 B1 = *(const float4*)&WT[k4 + 1][tx << 2];
      float4 B2 = *(const float4*)&WT[k4 + 2][tx << 2];
      float4 B3 = *(const float4*)&WT[k4 + 3][tx << 2];
      const float a[4][4] = {{A0.x,A0.y,A0.z,A0.w},{A1.x,A1.y,A1.z,A1.w},
                             {A2.x,A2.y,A2.z,A2.w},{A3.x,A3.y,A3.z,A3.w}};
      const float b[4][4] = {{B0.x,B0.y,B0.z,B0.w},{B1.x,B1.y,B1.z,B1.w},
                             {B2.x,B2.y,B2.z,B2.w},{B3.x,B3.y,B3.z,B3.w}};
#pragma unroll
      for (int i = 0; i < 4; ++i)
#pragma unroll
        for (int j = 0; j < 4; ++j)
          acc[i][j] += a[i][0]*b[0][j] + a[i][1]*b[1][j] + a[i][2]*b[2][j] + a[i][3]*b[3][j];
    }
  }
  const int c0 = n0 + (tx << 2);
  const float4 bv = *(const float4*)&bias[c0];
#pragma unroll
  for (int i = 0; i < 4; ++i) {
    const int m = m0 + (ty << 2) + i;
    float4 o = make_float4(acc[i][0] + bv.x, acc[i][1] + bv.y,
                           acc[i][2] + bv.z, acc[i][3] + bv.w);
    if (headsplit) {
      const int bb = m >> 11, s = m & 2047;
      *(float4*)&Y[(((size_t)(nt * NBATCH + bb) * SEQL + s) << 6) + (tx << 2)] = o;
    } else {
      *(float4*)&Y[((size_t)m << 9) + c0] = o;
    }
  }
}

// Fused attention v2 (see header comment).
__global__ __launch_bounds__(256) void attn_fused(const float* __restrict__ Q,
    const float* __restrict__ V, const float* __restrict__ U,
    float* __restrict__ logp, float* __restrict__ att)
{
  __shared__ float Qi[64][68];
  __shared__ float QjT[64][68];
  __shared__ unsigned short cand[64][128];
  __shared__ int ccnt[64];
  const int tid = threadIdx.x;
  const int tx = tid & 15, ty = tid >> 4;
  const int bh = ((blockIdx.x & 7) << 1) | ((blockIdx.x >> 3) & 1);
  const int rb = blockIdx.x >> 4;
  const int r0 = rb << 6;
  const float* Qh = Q + (((size_t)bh * SEQL) << 6);
  const float* Vh = V + (((size_t)bh * SEQL) << 6);
  if (tid < 64) ccnt[tid] = 0;
#pragma unroll
  for (int i = 0; i < 4; ++i) {
    const int f = (tid << 2) + i;
    const int r = f >> 4, k4 = (f & 15) << 2;
    *(float4*)&Qi[r][k4] = *(const float4*)&Qh[((size_t)(r0 + r) << 6) + k4];
  }
  float m1[4], l1[4], M2[4];
#pragma unroll
  for (int i = 0; i < 4; ++i) { m1[i] = -1e30f; l1[i] = 0.f; M2[i] = -1e30f; }
  __syncthreads();

  // ---- pass 1: stats + candidates (no global writes) ----
  for (int jt = 0; jt < 32; ++jt) {
    if (jt) __syncthreads();
#pragma unroll
    for (int i = 0; i < 4; ++i) {
      const int f = (tid << 2) + i;
      const int c = f >> 4, k4 = (f & 15) << 2;
      float4 w = *(const float4*)&Qh[((size_t)((jt << 6) + c) << 6) + k4];
      QjT[k4 + 0][c] = w.x; QjT[k4 + 1][c] = w.y; QjT[k4 + 2][c] = w.z; QjT[k4 + 3][c] = w.w;
    }
    __syncthreads();
    float s4[4][4] = {};
#pragma unroll 4
    for (int k4 = 0; k4 < 64; k4 += 4) {
      float4 A0 = *(const float4*)&Qi[(ty << 2) + 0][k4];
      float4 A1 = *(const float4*)&Qi[(ty << 2) + 1][k4];
      float4 A2 = *(const float4*)&Qi[(ty << 2) + 2][k4];
      float4 A3 = *(const float4*)&Qi[(ty << 2) + 3][k4];
      float4 B0 = *(const float4*)&QjT[k4 + 0][tx << 2];
      float4 B1 = *(const float4*)&QjT[k4 + 1][tx << 2];
      float4 B2 = *(const float4*)&QjT[k4 + 2][tx << 2];
      float4 B3 = *(const float4*)&QjT[k4 + 3][tx << 2];
      const float a[4][4] = {{A0.x,A0.y,A0.z,A0.w},{A1.x,A1.y,A1.z,A1.w},
                             {A2.x,A2.y,A2.z,A2.w},{A3.x,A3.y,A3.z,A3.w}};
      const float b[4][4] = {{B0.x,B0.y,B0.z,B0.w},{B1.x,B1.y,B1.z,B1.w},
                             {B2.x,B2.y,B2.z,B2.w},{B3.x,B3.y,B3.z,B3.w}};
#pragma unroll
      for (int i = 0; i < 4; ++i)
#pragma unroll
        for (int j = 0; j < 4; ++j)
          s4[i][j] += a[i][0]*b[0][j] + a[i][1]*b[1][j] + a[i][2]*b[2][j] + a[i][3]*b[3][j];
    }
#pragma unroll
    for (int i = 0; i < 4; ++i) {
      const int lr = (ty << 2) + i;
      const int gr = r0 + lr;
      const int gc0 = (jt << 6) + (tx << 2);
#pragma unroll
      for (int jj = 0; jj < 4; ++jj)
        if (gr == gc0 + jj) s4[i][jj] = -1e9f;
      const size_t rowb = ((size_t)bh * SEQL + gr) * SEQL;
      const float4 uu = *(const float4*)&U[rowb + gc0];
      const float t0 = s4[i][0] + gumbelf(uu.x);
      const float t1 = s4[i][1] + gumbelf(uu.y);
      const float t2 = s4[i][2] + gumbelf(uu.z);
      const float t3 = s4[i][3] + gumbelf(uu.w);
      // lane-local online log-softmax stats (merged once after the loop)
      const float sm = fmaxf(fmaxf(s4[i][0], s4[i][1]), fmaxf(s4[i][2], s4[i][3]));
      const float nm = fmaxf(m1[i], sm);
      const float es = __expf(s4[i][0] - nm) + __expf(s4[i][1] - nm)
                     + __expf(s4[i][2] - nm) + __expf(s4[i][3] - nm);
      l1[i] = l1[i] * __expf(m1[i] - nm) + es;
      m1[i] = nm;
      // global-running t-max (keeps candidate list tight, ~15/row)
      const float tm = bmax16(fmaxf(fmaxf(t0, t1), fmaxf(t2, t3)));
      M2[i] = fmaxf(M2[i], tm);
      const float thr = M2[i] - 0.62f;   // exp(x/T)==0 in fp32 for x<-0.588
      if (t0 > thr) { int z = atomicAdd(&ccnt[lr], 1); if (z < 128) cand[lr][z] = (unsigned short)(gc0 + 0); }
      if (t1 > thr) { int z = atomicAdd(&ccnt[lr], 1); if (z < 128) cand[lr][z] = (unsigned short)(gc0 + 1); }
      if (t2 > thr) { int z = atomicAdd(&ccnt[lr], 1); if (z < 128) cand[lr][z] = (unsigned short)(gc0 + 2); }
      if (t3 > thr) { int z = atomicAdd(&ccnt[lr], 1); if (z < 128) cand[lr][z] = (unsigned short)(gc0 + 3); }
    }
  }
  // ---- merge lane-local stats across the 16 tx lanes ----
  float lse[4];
#pragma unroll
  for (int i = 0; i < 4; ++i) {
#pragma unroll
    for (int d = 1; d < 16; d <<= 1) {
      const float om = __shfl_xor(m1[i], d);
      const float ol = __shfl_xor(l1[i], d);
      const float nm = fmaxf(m1[i], om);
      l1[i] = l1[i] * __expf(m1[i] - nm) + ol * __expf(om - nm);
      m1[i] = nm;
      M2[i] = fmaxf(M2[i], __shfl_xor(M2[i], d));
    }
    lse[i] = m1[i] + __logf(l1[i]);
  }
  __syncthreads();   // candidates from all waves visible

  // ---- candidate gather: att_out = softmax-sample @ V ----
#pragma unroll 1
  for (int i = 0; i < 4; ++i) {
    const int lr = (ty << 2) + i;
    const int gr = r0 + lr;
    int n = ccnt[lr]; n = (n < 128) ? n : 128;
    const size_t rowb = ((size_t)bh * SEQL + gr) * SEQL;
    const float4 qi = *(const float4*)&Qi[lr][tx << 2];
    float l2 = 0.f, ax = 0.f, ay = 0.f, az = 0.f, aw = 0.f;
    for (int c = 0; c < n; ++c) {
      const int j = cand[lr][c];
      const float4 qj = *(const float4*)&Qh[((size_t)j << 6) + (tx << 2)];
      float s = qi.x*qj.x + qi.y*qj.y + qi.z*qj.z + qi.w*qj.w;
      s = bsum16(s);
      if (j == gr) s = -1e9f;
      const float g = gumbelf(U[rowb + j]);
      const float p = __expf((s + g - M2[i]) / TEMPF);
      l2 += p;
      const float4 vv = *(const float4*)&Vh[((size_t)j << 6) + (tx << 2)];
      ax += p * vv.x; ay += p * vv.y; az += p * vv.z; aw += p * vv.w;
    }
    const float inv = 1.0f / l2;
    *(float4*)&att[(((size_t)bh * SEQL + gr) << 6) + (tx << 2)] =
        make_float4(ax * inv, ay * inv, az * inv, aw * inv);
  }

  // ---- pass 2: recompute QK (identical accumulation order), write logp ----
  for (int jt = 0; jt < 32; ++jt) {
    __syncthreads();
#pragma unroll
    for (int i = 0; i < 4; ++i) {
      const int f = (tid << 2) + i;
      const int c = f >> 4, k4 = (f & 15) << 2;
      float4 w = *(const float4*)&Qh[((size_t)((jt << 6) + c) << 6) + k4];
      QjT[k4 + 0][c] = w.x; QjT[k4 + 1][c] = w.y; QjT[k4 + 2][c] = w.z; QjT[k4 + 3][c] = w.w;
    }
    __syncthreads();
    float s4[4][4] = {};
#pragma unroll 4
    for (int k4 = 0; k4 < 64; k4 += 4) {
      float4 A0 = *(const float4*)&Qi[(ty << 2) + 0][k4];
      float4 A1 = *(const float4*)&Qi[(ty << 2) + 1][k4];
      float4 A2 = *(const float4*)&Qi[(ty << 2) + 2][k4];
      float4 A3 = *(const float4*)&Qi[(ty << 2) + 3][k4];
      float4 B0 = *(const float4*)&QjT[k4 + 0][tx << 2];
      float4 B1 = *(const float4*)&QjT[k4 + 1][tx << 2];
      float4 B2 = *(const float4*)&QjT[k4 + 2][tx << 2];
      float4 B3 = *(const float4*)&QjT[k4 + 3][tx << 2];
      const float a[4][4] = {{A0.x,A0.y,A0.z,A0.w},{A1.x,A1.y,A1.z,A1.w},
                             {A2.x,A2.y,A2.z,A2.w},{A3.x,A3.y,A3.z,A3.w}};
      const float b[4][4] = {{B0.x,B0.y,B0.z,B0.w},{B1.x,B1.y,B1.z,B1.w},
                             {B2.x,B2.y,B2.z,B2.w},{B3.x,B3.y,B3.z,B3.w}};
#pragma unroll
      for (int i = 0; i < 4; ++i)
#pragma unroll
        for (int j = 0; j < 4; ++j)
          s4[i][j] += a[i][0]*b[0][j] + a[i][1]*b[1][j] + a[i][2]*b[2][j] + a[i][3]*b[3][j];
    }
#pragma unroll
    for (int i = 0; i < 4; ++i) {
      const int gr = r0 + (ty << 2) + i;
      const int gc0 = (jt << 6) + (tx << 2);
#pragma unroll
      for (int jj = 0; jj < 4; ++jj)
        if (gr == gc0 + jj) s4[i][jj] = -1e9f;
      const size_t rowb = ((size_t)bh * SEQL + gr) * SEQL;
      *(float4*)&logp[rowb + gc0] = make_float4(s4[i][0] - lse[i], s4[i][1] - lse[i],
                                                s4[i][2] - lse[i], s4[i][3] - lse[i]);
    }
  }
}

// Per-head FF tube (64->128 relu ->64) + pairwise Gumbel-softmax (GS_DIM=2).
__global__ __launch_bounds__(128) void tubes(const float* __restrict__ att,
    const float* __restrict__ ff_w1, const float* __restrict__ ff_b1,
    const float* __restrict__ ff_w2, const float* __restrict__ ff_b2,
    const float* __restrict__ u_gs, float* __restrict__ gs)
{
  __shared__ float w1s[128 * 64];
  __shared__ float w2Ts[128 * 64];
  const int tid = threadIdx.x;
  const int n = blockIdx.x >> 5;
  const int chunk = blockIdx.x & 31;
  const float* w1 = ff_w1 + n * 8192;
  const float* w2 = ff_w2 + n * 8192;
#pragma unroll
  for (int i = 0; i < 16; ++i) {
    const int f = i * 128 + tid;
    ((float4*)w1s)[f] = ((const float4*)w1)[f];
    const int o = f >> 5, j4 = (f & 31) << 2;
    float4 v = ((const float4*)w2)[f];
    w2Ts[(j4 + 0) * 64 + o] = v.x; w2Ts[(j4 + 1) * 64 + o] = v.y;
    w2Ts[(j4 + 2) * 64 + o] = v.z; w2Ts[(j4 + 3) * 64 + o] = v.w;
  }
  __syncthreads();
  const int token = chunk * 128 + tid;
  const int b = token >> 11, s = token & 2047;
  const float* ap = att + (((size_t)(n * NBATCH + b) * SEQL + s) << 6);
  float a[64];
#pragma unroll
  for (int k4 = 0; k4 < 64; k4 += 4) {
    float4 v = *(const float4*)&ap[k4];
    a[k4] = v.x; a[k4 + 1] = v.y; a[k4 + 2] = v.z; a[k4 + 3] = v.w;
  }
  float dm[64] = {};
  for (int j = 0; j < 128; ++j) {
    float h = ff_b1[n * 128 + j];
#pragma unroll
    for (int k4 = 0; k4 < 64; k4 += 4) {
      float4 w = *(const float4*)&w1s[(j << 6) + k4];
      h += w.x * a[k4] + w.y * a[k4 + 1] + w.z * a[k4 + 2] + w.w * a[k4 + 3];
    }
    h = fmaxf(h, 0.f);
#pragma unroll
    for (int o4 = 0; o4 < 64; o4 += 4) {
      float4 w = *(const float4*)&w2Ts[(j << 6) + o4];
      dm[o4] += w.x * h; dm[o4 + 1] += w.y * h; dm[o4 + 2] += w.z * h; dm[o4 + 3] += w.w * h;
    }
  }
  const float* up = u_gs + (((size_t)(n * NBATCH + b) * SEQL + s) << 6);
  float* gp = gs + (((size_t)(b * SEQL + s)) << 9) + (n << 6);
  const float* b2 = ff_b2 + (n << 6);
#pragma unroll
  for (int q = 0; q < 16; ++q) {
    const float4 uu = *(const float4*)&up[q << 2];
    const float d0 = dm[(q << 2) + 0] + b2[(q << 2) + 0];
    const float d1 = dm[(q << 2) + 1] + b2[(q << 2) + 1];
    const float d2 = dm[(q << 2) + 2] + b2[(q << 2) + 2];
    const float d3 = dm[(q << 2) + 3] + b2[(q << 2) + 3];
    const float z0 = d0 + gumbelf(uu.x), z1 = d1 + gumbelf(uu.y);
    const float z2 = d2 + gumbelf(uu.z), z3 = d3 + gumbelf(uu.w);
    const float ma = fmaxf(z0, z1), mb = fmaxf(z2, z3);
    const float e0 = __expf((z0 - ma) / TEMPF), e1 = __expf((z1 - ma) / TEMPF);
    const float e2 = __expf((z2 - mb) / TEMPF), e3 = __expf((z3 - mb) / TEMPF);
    const float ia = 1.0f / (e0 + e1), ib = 1.0f / (e2 + e3);
    *(float4*)&gp[q << 2] = make_float4(e0 * ia, e1 * ia, e2 * ib, e3 * ib);
  }
}

extern "C" void kernel_launch(void* const* d_in, const int* in_sizes, int n_in,
                              void* d_out, int out_size, void* d_ws, size_t ws_size,
                              hipStream_t stream) {
  const float* kq    = (const float*)d_in[0];
  const float* v     = (const float*)d_in[1];
  const float* w_kq  = (const float*)d_in[2];
  const float* b_kq  = (const float*)d_in[3];
  const float* w_v   = (const float*)d_in[4];
  const float* b_v   = (const float*)d_in[5];
  const float* ff_w1 = (const float*)d_in[6];
  const float* ff_b1 = (const float*)d_in[7];
  const float* ff_w2 = (const float*)d_in[8];
  const float* ff_b2 = (const float*)d_in[9];
  const float* fc_w  = (const float*)d_in[10];
  const float* fc_b  = (const float*)d_in[11];
  const float* u_at  = (const float*)d_in[12];
  const float* u_gs  = (const float*)d_in[13];
  float* out  = (float*)d_out;
  float* logp = out + (size_t)NBATCH * SEQL * 512;
  float* ws   = (float*)d_ws;
  float* Q    = ws;
  float* V    = Q + (size_t)BHN * SEQL * 64;
  float* att  = V + (size_t)BHN * SEQL * 64;
  float* gs   = att + (size_t)BHN * SEQL * 64;

  gemm512<<<512, 256, 0, stream>>>(kq, w_kq, b_kq, Q, 1);
  gemm512<<<512, 256, 0, stream>>>(v, w_v, b_v, V, 1);
  attn_fused<<<512, 256, 0, stream>>>(Q, V, u_at, logp, att);
  tubes<<<256, 128, 0, stream>>>(att, ff_w1, ff_b1, ff_w2, ff_b2, u_gs, gs);
  gemm512<<<512, 256, 0, stream>>>(gs, fc_w, fc_b, out, 0);
}